// Round 1
// baseline (19103.470 us; speedup 1.0000x reference)
//
#include <hip/hip_runtime.h>
#include <math.h>

#define N_NODES 100000
#define N_EDGES 1600000
#define MAX_ITER 50

// ws layout (bytes):
//   acc   : N_NODES*5*8 = 4,000,000   (Q32.32 fixed-point accumulators)
//   state : N_NODES*5*4 = 2,000,000
//   old   : N_NODES*5*4 = 2,000,000
//   flags : (MAX_ITER+1)*4 = 204
//   kcnt  : 4
// total ~8.0 MB

__global__ void init0_kernel(int* flags, int* kcnt) {
    int t = threadIdx.x;
    if (t <= MAX_ITER) flags[t] = 0;
    if (t == 0) *kcnt = 0;
}

__global__ void init1_kernel(const float* __restrict__ state_init,
                             const float* __restrict__ old_init,
                             float* __restrict__ state,
                             float* __restrict__ oldst,
                             unsigned long long* __restrict__ acc,
                             int* __restrict__ flags) {
    int n = blockIdx.x * blockDim.x + threadIdx.x;
    if (n >= N_NODES) return;
    float ss = 0.f;
#pragma unroll
    for (int j = 0; j < 5; ++j) {
        float s = state_init[n * 5 + j];
        float o = old_init[n * 5 + j];
        state[n * 5 + j] = s;
        oldst[n * 5 + j] = o;
        acc[n * 5 + j] = 0ULL;
        float d = s - o;
        ss += d * d;
    }
    int pred = sqrtf(ss + 1e-11f) > 0.01f;
    unsigned long long m = __ballot(pred);
    if ((threadIdx.x & 63) == 0 && m) atomicOr(&flags[0], 1);
}

__global__ __launch_bounds__(256) void edge_kernel(
    const float* __restrict__ edge_feat,
    const int* __restrict__ edge_src,
    const int* __restrict__ arc_rows,
    const float* __restrict__ arc_vals,
    const float* __restrict__ state,
    unsigned long long* __restrict__ acc,
    const float* __restrict__ W1, const float* __restrict__ b1,
    const float* __restrict__ W2, const float* __restrict__ b2,
    const int* __restrict__ flag) {
    if (*flag == 0) return;
    int e = blockIdx.x * blockDim.x + threadIdx.x;
    if (e >= N_EDGES) return;

    float in[13];
    const float4* efp = (const float4*)(edge_feat + (size_t)e * 8);
    float4 f0 = efp[0];
    float4 f1 = efp[1];
    in[0] = f0.x; in[1] = f0.y; in[2] = f0.z; in[3] = f0.w;
    in[4] = f1.x; in[5] = f1.y; in[6] = f1.z; in[7] = f1.w;
    int src = edge_src[e];
#pragma unroll
    for (int j = 0; j < 5; ++j) in[8 + j] = state[src * 5 + j];

    float h1[15];
#pragma unroll
    for (int j = 0; j < 15; ++j) {
        float a = b1[j];
#pragma unroll
        for (int i = 0; i < 13; ++i) a += in[i] * W1[i * 15 + j];
        h1[j] = tanhf(a);
    }

    float av = arc_vals[e];
    int row = arc_rows[e];
    unsigned long long* ap = acc + (size_t)row * 5;
#pragma unroll
    for (int j = 0; j < 5; ++j) {
        float a = b2[j];
#pragma unroll
        for (int i = 0; i < 15; ++i) a += h1[i] * W2[i * 5 + j];
        float v = tanhf(a) * av;
        long long q = (long long)((double)v * 4294967296.0);
        atomicAdd(&ap[j], (unsigned long long)q);
    }
}

__global__ void node_kernel(float* __restrict__ state,
                            float* __restrict__ oldst,
                            unsigned long long* __restrict__ acc,
                            const int* __restrict__ flag_cur,
                            int* __restrict__ flag_next,
                            int* __restrict__ kcnt) {
    if (*flag_cur == 0) return;
    int n = blockIdx.x * blockDim.x + threadIdx.x;
    if (n >= N_NODES) return;
    if (n == 0) *kcnt += 1;
    float ss = 0.f;
#pragma unroll
    for (int j = 0; j < 5; ++j) {
        unsigned long long u = acc[n * 5 + j];
        acc[n * 5 + j] = 0ULL;
        float nv = (float)((double)(long long)u * (1.0 / 4294967296.0));
        float pv = state[n * 5 + j];
        oldst[n * 5 + j] = pv;
        state[n * 5 + j] = nv;
        float d = nv - pv;
        ss += d * d;
    }
    int pred = sqrtf(ss + 1e-11f) > 0.01f;
    unsigned long long m = __ballot(pred);
    if ((threadIdx.x & 63) == 0 && m) atomicOr(flag_next, 1);
}

__global__ void final_kernel(const float* __restrict__ state,
                             const float* __restrict__ W3, const float* __restrict__ b3,
                             const float* __restrict__ W4, const float* __restrict__ b4,
                             const int* __restrict__ kcnt,
                             float* __restrict__ out) {
    int n = blockIdx.x * blockDim.x + threadIdx.x;
    if (n == 0) out[(size_t)N_NODES * 7] = (float)(*kcnt);
    if (n >= N_NODES) return;
    float st[5];
#pragma unroll
    for (int j = 0; j < 5; ++j) st[j] = state[n * 5 + j];
    float o1[10];
#pragma unroll
    for (int j = 0; j < 10; ++j) {
        float a = b3[j];
#pragma unroll
        for (int i = 0; i < 5; ++i) a += st[i] * W3[i * 10 + j];
        o1[j] = tanhf(a);
    }
    float z[7];
    float m = -1e30f;
#pragma unroll
    for (int j = 0; j < 7; ++j) {
        float a = b4[j];
#pragma unroll
        for (int i = 0; i < 10; ++i) a += o1[i] * W4[i * 7 + j];
        z[j] = a;
        m = fmaxf(m, a);
    }
    float s = 0.f;
#pragma unroll
    for (int j = 0; j < 7; ++j) { z[j] = expf(z[j] - m); s += z[j]; }
    float inv = 1.f / s;
#pragma unroll
    for (int j = 0; j < 7; ++j) out[(size_t)n * 7 + j] = z[j] * inv;
}

extern "C" void kernel_launch(void* const* d_in, const int* in_sizes, int n_in,
                              void* d_out, int out_size, void* d_ws, size_t ws_size,
                              hipStream_t stream) {
    const float* edge_feat  = (const float*)d_in[0];
    const int*   edge_src   = (const int*)d_in[1];
    const int*   arc_rows   = (const int*)d_in[2];
    const float* arc_vals   = (const float*)d_in[3];
    const float* state_init = (const float*)d_in[4];
    const float* old_init   = (const float*)d_in[5];
    const float* W1 = (const float*)d_in[6];
    const float* b1 = (const float*)d_in[7];
    const float* W2 = (const float*)d_in[8];
    const float* b2 = (const float*)d_in[9];
    const float* W3 = (const float*)d_in[10];
    const float* b3 = (const float*)d_in[11];
    const float* W4 = (const float*)d_in[12];
    const float* b4 = (const float*)d_in[13];

    char* ws = (char*)d_ws;
    unsigned long long* acc = (unsigned long long*)ws;        // 4,000,000 B
    float* state = (float*)(ws + 4000000);                    // 2,000,000 B
    float* oldst = (float*)(ws + 6000000);                    // 2,000,000 B
    int* flags = (int*)(ws + 8000000);                        // 204 B
    int* kcnt = (int*)(ws + 8000000 + 204);                   // 4 B

    hipLaunchKernelGGL(init0_kernel, dim3(1), dim3(64), 0, stream, flags, kcnt);
    int nb = (N_NODES + 255) / 256;
    hipLaunchKernelGGL(init1_kernel, dim3(nb), dim3(256), 0, stream,
                       state_init, old_init, state, oldst, acc, flags);
    int eb = (N_EDGES + 255) / 256;
    for (int it = 0; it < MAX_ITER; ++it) {
        hipLaunchKernelGGL(edge_kernel, dim3(eb), dim3(256), 0, stream,
                           edge_feat, edge_src, arc_rows, arc_vals, state, acc,
                           W1, b1, W2, b2, flags + it);
        hipLaunchKernelGGL(node_kernel, dim3(nb), dim3(256), 0, stream,
                           state, oldst, acc, flags + it, flags + it + 1, kcnt);
    }
    hipLaunchKernelGGL(final_kernel, dim3(nb), dim3(256), 0, stream,
                       state, W3, b3, W4, b4, kcnt, (float*)d_out);
}

// Round 2
// 7939.670 us; speedup vs baseline: 2.4061x; 2.4061x over previous
//
#include <hip/hip_runtime.h>
#include <math.h>

#define N_NODES 100000
#define N_EDGES 1600000
#define MAX_ITER 50
#define THRESH 0.01f
#define SCAN_CHUNK 1024
#define NBLK_SCAN 98   // ceil(100000/1024)

// ws layout (16B-aligned offsets, total ~11.2 MB):
//   off   [N_NODES+1] int : 0        .. 400,016
//   cnt   [N_NODES]   int : 400,016  .. 800,016   (histogram, then cursor)
//   bsum  [NBLK_SCAN] int : 800,016  .. 800,528
//   flags [51]+kcnt   int : 800,528  .. 800,752
//   perm  [N_EDGES]   int : 800,752  .. 7,200,752
//   buf0  [N_NODES*5] f32 : 7,200,752 .. 9,200,752
//   buf1  [N_NODES*5] f32 : 9,200,752 .. 11,200,752

__device__ __forceinline__ float fast_tanh(float x) {
    float ax = fabsf(x);
    float e = __expf(2.0f * ax);                       // v_mul + v_exp
    float r = 1.0f - 2.0f * __builtin_amdgcn_rcpf(e + 1.0f);
    return copysignf(r, x);                            // exact ±1 for |x| large
}

__global__ void zero_ints(int* p, int n) {
    int i = blockIdx.x * blockDim.x + threadIdx.x;
    if (i < n) p[i] = 0;
}

__global__ void hist_kernel(const int* __restrict__ rows, int* __restrict__ cnt) {
    int e = blockIdx.x * blockDim.x + threadIdx.x;
    if (e < N_EDGES) atomicAdd(&cnt[rows[e]], 1);
}

__global__ __launch_bounds__(256) void scan1_kernel(const int* __restrict__ cnt,
                                                    int* __restrict__ off,
                                                    int* __restrict__ bsum) {
    __shared__ int sm[256];
    int b = blockIdx.x, t = threadIdx.x;
    int base = b * SCAN_CHUNK + t * 4;
    int v[4];
    int tsum = 0;
#pragma unroll
    for (int j = 0; j < 4; ++j) {
        v[j] = (base + j < N_NODES) ? cnt[base + j] : 0;
        tsum += v[j];
    }
    int val = tsum;
    sm[t] = val;
    __syncthreads();
    for (int d = 1; d < 256; d <<= 1) {
        int x = (t >= d) ? sm[t - d] : 0;
        __syncthreads();
        val += x;
        sm[t] = val;
        __syncthreads();
    }
    int run = val - tsum;  // exclusive start for this thread
#pragma unroll
    for (int j = 0; j < 4; ++j) {
        if (base + j < N_NODES) off[base + j] = run;
        run += v[j];
    }
    if (t == 255) bsum[b] = val;  // block total
}

__global__ __launch_bounds__(128) void scan2_kernel(int* __restrict__ bsum) {
    __shared__ int sm[128];
    int t = threadIdx.x;
    int v = (t < NBLK_SCAN) ? bsum[t] : 0;
    int val = v;
    sm[t] = val;
    __syncthreads();
    for (int d = 1; d < 128; d <<= 1) {
        int x = (t >= d) ? sm[t - d] : 0;
        __syncthreads();
        val += x;
        sm[t] = val;
        __syncthreads();
    }
    if (t < NBLK_SCAN) bsum[t] = val - v;  // exclusive
}

__global__ __launch_bounds__(256) void scan3_kernel(int* __restrict__ off,
                                                    const int* __restrict__ bsum) {
    int b = blockIdx.x, t = threadIdx.x;
    int add = bsum[b];
    int base = b * SCAN_CHUNK + t * 4;
#pragma unroll
    for (int j = 0; j < 4; ++j)
        if (base + j < N_NODES) off[base + j] += add;
    if (b == 0 && t == 0) off[N_NODES] = N_EDGES;
}

__global__ void scatter_kernel(const int* __restrict__ rows,
                               const int* __restrict__ off,
                               int* __restrict__ cur,
                               int* __restrict__ perm) {
    int e = blockIdx.x * blockDim.x + threadIdx.x;
    if (e >= N_EDGES) return;
    int r = rows[e];
    int p = off[r] + atomicAdd(&cur[r], 1);
    perm[p] = e;
}

__global__ void init_state_kernel(const float* __restrict__ state_init,
                                  const float* __restrict__ old_init,
                                  float* __restrict__ buf0,
                                  int* __restrict__ flags) {
    int n = blockIdx.x * blockDim.x + threadIdx.x;
    if (n >= N_NODES) return;
    float ss = 0.f;
#pragma unroll
    for (int j = 0; j < 5; ++j) {
        float s = state_init[n * 5 + j];
        float o = old_init[n * 5 + j];
        buf0[n * 5 + j] = s;
        float d = s - o;
        ss += d * d;
    }
    int pred = sqrtf(ss + 1e-11f) > THRESH;
    unsigned long long m = __ballot(pred);
    if ((threadIdx.x & 63) == 0 && m) atomicOr(&flags[0], 1);
}

// Fused per-iteration kernel: 2 threads per node, CSR gather, register accumulate.
__global__ __launch_bounds__(256) void iter_kernel(
    const int* __restrict__ off, const int* __restrict__ perm,
    const float* __restrict__ edge_feat, const int* __restrict__ edge_src,
    const float* __restrict__ arc_vals,
    const float* __restrict__ sprev, float* __restrict__ snext,
    const float* __restrict__ W1, const float* __restrict__ b1,
    const float* __restrict__ W2, const float* __restrict__ b2,
    const int* __restrict__ flag_cur, int* __restrict__ flag_next,
    int* __restrict__ kcnt) {
    int t = blockIdx.x * blockDim.x + threadIdx.x;
    int n = t >> 1;
    if (n >= N_NODES) return;
    int half = t & 1;
    bool active = (*flag_cur != 0);
    if (!active) {
        // converged: state must remain unchanged; propagate to next buffer
        if (half == 0) {
#pragma unroll
            for (int j = 0; j < 5; ++j) snext[n * 5 + j] = sprev[n * 5 + j];
        }
        return;
    }
    if (t == 0) *kcnt += 1;

    int p0 = off[n], p1 = off[n + 1];
    float acc[5] = {0.f, 0.f, 0.f, 0.f, 0.f};
    for (int p = p0 + half; p < p1; p += 2) {
        int e = perm[p];
        const float4* efp = (const float4*)(edge_feat + (size_t)e * 8);
        float4 f0 = efp[0];
        float4 f1 = efp[1];
        int src = edge_src[e];
        float av = arc_vals[e];
        float in[13];
        in[0] = f0.x; in[1] = f0.y; in[2] = f0.z; in[3] = f0.w;
        in[4] = f1.x; in[5] = f1.y; in[6] = f1.z; in[7] = f1.w;
#pragma unroll
        for (int j = 0; j < 5; ++j) in[8 + j] = sprev[src * 5 + j];

        float h1[15];
#pragma unroll
        for (int j = 0; j < 15; ++j) {
            float a = b1[j];
#pragma unroll
            for (int i = 0; i < 13; ++i) a += in[i] * W1[i * 15 + j];
            h1[j] = fast_tanh(a);
        }
#pragma unroll
        for (int j = 0; j < 5; ++j) {
            float a = b2[j];
#pragma unroll
            for (int i = 0; i < 15; ++i) a += h1[i] * W2[i * 5 + j];
            acc[j] += fast_tanh(a) * av;
        }
    }
    // combine the two halves of each node (lanes 2k, 2k+1)
#pragma unroll
    for (int j = 0; j < 5; ++j) acc[j] += __shfl_xor(acc[j], 1, 64);

    int pred = 0;
    if (half == 0) {
        float ss = 0.f;
#pragma unroll
        for (int j = 0; j < 5; ++j) {
            float pv = sprev[n * 5 + j];
            snext[n * 5 + j] = acc[j];
            float d = acc[j] - pv;
            ss += d * d;
        }
        pred = sqrtf(ss + 1e-11f) > THRESH;
    }
    unsigned long long m = __ballot(pred);
    if ((threadIdx.x & 63) == 0 && m) atomicOr(flag_next, 1);
}

__global__ void final_kernel(const float* __restrict__ state,
                             const float* __restrict__ W3, const float* __restrict__ b3,
                             const float* __restrict__ W4, const float* __restrict__ b4,
                             const int* __restrict__ kcnt,
                             float* __restrict__ out) {
    int n = blockIdx.x * blockDim.x + threadIdx.x;
    if (n == 0) out[(size_t)N_NODES * 7] = (float)(*kcnt);
    if (n >= N_NODES) return;
    float st[5];
#pragma unroll
    for (int j = 0; j < 5; ++j) st[j] = state[n * 5 + j];
    float o1[10];
#pragma unroll
    for (int j = 0; j < 10; ++j) {
        float a = b3[j];
#pragma unroll
        for (int i = 0; i < 5; ++i) a += st[i] * W3[i * 10 + j];
        o1[j] = tanhf(a);
    }
    float z[7];
    float m = -1e30f;
#pragma unroll
    for (int j = 0; j < 7; ++j) {
        float a = b4[j];
#pragma unroll
        for (int i = 0; i < 10; ++i) a += o1[i] * W4[i * 7 + j];
        z[j] = a;
        m = fmaxf(m, a);
    }
    float s = 0.f;
#pragma unroll
    for (int j = 0; j < 7; ++j) { z[j] = expf(z[j] - m); s += z[j]; }
    float inv = 1.f / s;
#pragma unroll
    for (int j = 0; j < 7; ++j) out[(size_t)n * 7 + j] = z[j] * inv;
}

extern "C" void kernel_launch(void* const* d_in, const int* in_sizes, int n_in,
                              void* d_out, int out_size, void* d_ws, size_t ws_size,
                              hipStream_t stream) {
    const float* edge_feat  = (const float*)d_in[0];
    const int*   edge_src   = (const int*)d_in[1];
    const int*   arc_rows   = (const int*)d_in[2];
    const float* arc_vals   = (const float*)d_in[3];
    const float* state_init = (const float*)d_in[4];
    const float* old_init   = (const float*)d_in[5];
    const float* W1 = (const float*)d_in[6];
    const float* b1 = (const float*)d_in[7];
    const float* W2 = (const float*)d_in[8];
    const float* b2 = (const float*)d_in[9];
    const float* W3 = (const float*)d_in[10];
    const float* b3 = (const float*)d_in[11];
    const float* W4 = (const float*)d_in[12];
    const float* b4 = (const float*)d_in[13];

    char* ws = (char*)d_ws;
    int*   off   = (int*)(ws + 0);
    int*   cnt   = (int*)(ws + 400016);
    int*   bsum  = (int*)(ws + 800016);
    int*   flags = (int*)(ws + 800528);     // 51 ints + kcnt
    int*   kcnt  = flags + 51;
    int*   perm  = (int*)(ws + 800752);
    float* buf0  = (float*)(ws + 7200752);
    float* buf1  = (float*)(ws + 9200752);

    int nb = (N_NODES + 255) / 256;
    int eb = (N_EDGES + 255) / 256;

    // ---- CSR build (once per call; deterministic up to fp-benign order) ----
    hipLaunchKernelGGL(zero_ints, dim3(nb), dim3(256), 0, stream, cnt, N_NODES);
    hipLaunchKernelGGL(zero_ints, dim3(1), dim3(64), 0, stream, flags, 52);
    hipLaunchKernelGGL(hist_kernel, dim3(eb), dim3(256), 0, stream, arc_rows, cnt);
    hipLaunchKernelGGL(scan1_kernel, dim3(NBLK_SCAN), dim3(256), 0, stream, cnt, off, bsum);
    hipLaunchKernelGGL(scan2_kernel, dim3(1), dim3(128), 0, stream, bsum);
    hipLaunchKernelGGL(scan3_kernel, dim3(NBLK_SCAN), dim3(256), 0, stream, off, bsum);
    hipLaunchKernelGGL(zero_ints, dim3(nb), dim3(256), 0, stream, cnt, N_NODES);  // cursors
    hipLaunchKernelGGL(scatter_kernel, dim3(eb), dim3(256), 0, stream, arc_rows, off, cnt, perm);
    hipLaunchKernelGGL(init_state_kernel, dim3(nb), dim3(256), 0, stream,
                       state_init, old_init, buf0, flags);

    // ---- 50 fused iterations, ping-pong state buffers ----
    int ib = (2 * N_NODES + 255) / 256;
    for (int it = 0; it < MAX_ITER; ++it) {
        const float* sp = (it & 1) ? buf1 : buf0;
        float*       sn = (it & 1) ? buf0 : buf1;
        hipLaunchKernelGGL(iter_kernel, dim3(ib), dim3(256), 0, stream,
                           off, perm, edge_feat, edge_src, arc_vals,
                           sp, sn, W1, b1, W2, b2,
                           flags + it, flags + it + 1, kcnt);
    }

    // 50 iterations (even) -> final state in buf0
    hipLaunchKernelGGL(final_kernel, dim3(nb), dim3(256), 0, stream,
                       buf0, W3, b3, W4, b4, kcnt, (float*)d_out);
}

// Round 3
// 5463.880 us; speedup vs baseline: 3.4963x; 1.4531x over previous
//
#include <hip/hip_runtime.h>
#include <math.h>

#define N_NODES 100000
#define N_EDGES 1600000
#define MAX_ITER 50
#define THRESH 0.01f
#define SCAN_CHUNK 1024
#define NBLK_SCAN 98   // ceil(100000/1024)

// ---------- FULL ws layout (needs 71,201,664 B) ----------
//   off    : 0          (N+1 ints, pad to 400,128)
//   cnt    : 400,128    (N ints)
//   flags  : 800,128    (51 ints + kcnt; pad 256)
//   wconst : 800,384    (W1T 195 | b1 15 | W2T 75 | b2 5 = 290 f, pad 1280)
//   buf0   : 801,664    (N*8 f32, padded stride 8 = 3.2 MB)
//   buf1   : 4,001,664  (3.2 MB)
//   meta   : 7,201,664  (E int2 = 12.8 MB)   (src, val bits) in CSR order
//   featg  : 20,001,664 (E*8 f32 = 51.2 MB)  edge features in CSR order
#define WS_FULL_NEED 71201664ULL

// ---------- FALLBACK ws layout (R2, needs ~11.2 MB) ----------
//   off 0..400,016 | cnt 400,016 | bsum 800,016 | flags 800,528 | perm 800,752
//   fbuf0 7,200,752 | fbuf1 9,200,752  (stride-5 buffers)

__device__ __forceinline__ float fast_tanh(float x) {
    float ax = fabsf(x);
    float e = __expf(2.0f * ax);
    float r = 1.0f - 2.0f * __builtin_amdgcn_rcpf(e + 1.0f);
    return copysignf(r, x);
}

__global__ void zero_ints(int* p, int n) {
    int i = blockIdx.x * blockDim.x + threadIdx.x;
    if (i < n) p[i] = 0;
}

__global__ void hist_kernel(const int* __restrict__ rows, int* __restrict__ cnt) {
    int e = blockIdx.x * blockDim.x + threadIdx.x;
    if (e < N_EDGES) atomicAdd(&cnt[rows[e]], 1);
}

__global__ __launch_bounds__(256) void scan1_kernel(const int* __restrict__ cnt,
                                                    int* __restrict__ off,
                                                    int* __restrict__ bsum) {
    __shared__ int sm[256];
    int b = blockIdx.x, t = threadIdx.x;
    int base = b * SCAN_CHUNK + t * 4;
    int v[4];
    int tsum = 0;
#pragma unroll
    for (int j = 0; j < 4; ++j) {
        v[j] = (base + j < N_NODES) ? cnt[base + j] : 0;
        tsum += v[j];
    }
    int val = tsum;
    sm[t] = val;
    __syncthreads();
    for (int d = 1; d < 256; d <<= 1) {
        int x = (t >= d) ? sm[t - d] : 0;
        __syncthreads();
        val += x;
        sm[t] = val;
        __syncthreads();
    }
    int run = val - tsum;
#pragma unroll
    for (int j = 0; j < 4; ++j) {
        if (base + j < N_NODES) off[base + j] = run;
        run += v[j];
    }
    if (t == 255) bsum[b] = val;
}

__global__ __launch_bounds__(128) void scan2_kernel(int* __restrict__ bsum) {
    __shared__ int sm[128];
    int t = threadIdx.x;
    int v = (t < NBLK_SCAN) ? bsum[t] : 0;
    int val = v;
    sm[t] = val;
    __syncthreads();
    for (int d = 1; d < 128; d <<= 1) {
        int x = (t >= d) ? sm[t - d] : 0;
        __syncthreads();
        val += x;
        sm[t] = val;
        __syncthreads();
    }
    if (t < NBLK_SCAN) bsum[t] = val - v;
}

__global__ __launch_bounds__(256) void scan3_kernel(int* __restrict__ off,
                                                    const int* __restrict__ bsum) {
    int b = blockIdx.x, t = threadIdx.x;
    int add = bsum[b];
    int base = b * SCAN_CHUNK + t * 4;
#pragma unroll
    for (int j = 0; j < 4; ++j)
        if (base + j < N_NODES) off[base + j] += add;
    if (b == 0 && t == 0) off[N_NODES] = N_EDGES;
}

// FULL path: scatter edge payloads directly into CSR order.
__global__ void scatter_build(const int* __restrict__ rows,
                              const int* __restrict__ esrc,
                              const float* __restrict__ evals,
                              const float* __restrict__ efeat,
                              const int* __restrict__ off,
                              int* __restrict__ cur,
                              float* __restrict__ featg,
                              int2* __restrict__ meta) {
    int e = blockIdx.x * blockDim.x + threadIdx.x;
    if (e >= N_EDGES) return;
    int r = rows[e];
    int p = off[r] + atomicAdd(&cur[r], 1);
    const float4* fp = (const float4*)(efeat + (size_t)e * 8);
    float4 a = fp[0], b = fp[1];
    float4* gp = (float4*)(featg + (size_t)p * 8);
    gp[0] = a; gp[1] = b;
    meta[p] = make_int2(esrc[e], __float_as_int(evals[e]));
}

// FALLBACK path: just the permutation.
__global__ void scatter_kernel(const int* __restrict__ rows,
                               const int* __restrict__ off,
                               int* __restrict__ cur,
                               int* __restrict__ perm) {
    int e = blockIdx.x * blockDim.x + threadIdx.x;
    if (e >= N_EDGES) return;
    int r = rows[e];
    int p = off[r] + atomicAdd(&cur[r], 1);
    perm[p] = e;
}

__global__ void wprep_kernel(const float* __restrict__ W1, const float* __restrict__ b1,
                             const float* __restrict__ W2, const float* __restrict__ b2,
                             float* __restrict__ wc) {
    int t = threadIdx.x;
    for (int idx = t; idx < 195; idx += 256) { int j = idx / 13, i = idx % 13; wc[idx] = W1[i * 15 + j]; }
    for (int idx = t; idx < 15; idx += 256) wc[195 + idx] = b1[idx];
    for (int idx = t; idx < 75; idx += 256) { int j = idx / 15, i = idx % 15; wc[210 + idx] = W2[i * 5 + j]; }
    for (int idx = t; idx < 5; idx += 256) wc[285 + idx] = b2[idx];
}

// FULL path init: padded stride-8 state buffer.
__global__ void init_state8_kernel(const float* __restrict__ state_init,
                                   const float* __restrict__ old_init,
                                   float* __restrict__ buf0,
                                   int* __restrict__ flags) {
    int n = blockIdx.x * blockDim.x + threadIdx.x;
    if (n >= N_NODES) return;
    float ss = 0.f;
    float s[5];
#pragma unroll
    for (int j = 0; j < 5; ++j) {
        s[j] = state_init[n * 5 + j];
        float d = s[j] - old_init[n * 5 + j];
        ss += d * d;
    }
    float4 o0 = {s[0], s[1], s[2], s[3]};
    float4 o1 = {s[4], 0.f, 0.f, 0.f};
    ((float4*)(buf0 + (size_t)n * 8))[0] = o0;
    ((float4*)(buf0 + (size_t)n * 8))[1] = o1;
    int pred = sqrtf(ss + 1e-11f) > THRESH;
    unsigned long long m = __ballot(pred);
    if ((threadIdx.x & 63) == 0 && m) atomicOr(&flags[0], 1);
}

// FULL path hot kernel: 4 threads/node, CSR-ordered streams, register accumulate.
__global__ __launch_bounds__(256) void iter4_kernel(
    const int* __restrict__ off,
    const float* __restrict__ featg,
    const int2* __restrict__ meta,
    const float* __restrict__ sprev,   // stride 8
    float* __restrict__ snext,         // stride 8
    const float* __restrict__ wc,
    const int* __restrict__ flag_cur, int* __restrict__ flag_next,
    int* __restrict__ kcnt) {
    int t = blockIdx.x * blockDim.x + threadIdx.x;
    int n = t >> 2;
    if (n >= N_NODES) return;
    int q = t & 3;
    if (*flag_cur == 0) {
        if (q == 0) {
            float4 a = ((const float4*)(sprev + (size_t)n * 8))[0];
            float4 b = ((const float4*)(sprev + (size_t)n * 8))[1];
            ((float4*)(snext + (size_t)n * 8))[0] = a;
            ((float4*)(snext + (size_t)n * 8))[1] = b;
        }
        return;
    }
    if (t == 0) *kcnt += 1;
    const float* W1T = wc;          // [15][13]
    const float* B1  = wc + 195;
    const float* W2T = wc + 210;    // [5][15]
    const float* B2  = wc + 285;

    int p0 = off[n], p1 = off[n + 1];
    float acc[5] = {0.f, 0.f, 0.f, 0.f, 0.f};
    for (int p = p0 + q; p < p1; p += 4) {
        const float4* fp = (const float4*)(featg + (size_t)p * 8);
        float4 f0 = fp[0], f1 = fp[1];
        int2 mv = meta[p];
        int src = mv.x;
        float av = __int_as_float(mv.y);
        float4 s0 = ((const float4*)(sprev + (size_t)src * 8))[0];
        float s4 = sprev[(size_t)src * 8 + 4];
        float in[13] = {f0.x, f0.y, f0.z, f0.w, f1.x, f1.y, f1.z, f1.w,
                        s0.x, s0.y, s0.z, s0.w, s4};
        float h1[15];
#pragma unroll
        for (int j = 0; j < 15; ++j) {
            float a = B1[j];
#pragma unroll
            for (int i = 0; i < 13; ++i) a += in[i] * W1T[j * 13 + i];
            h1[j] = fast_tanh(a);
        }
#pragma unroll
        for (int j = 0; j < 5; ++j) {
            float a = B2[j];
#pragma unroll
            for (int i = 0; i < 15; ++i) a += h1[i] * W2T[j * 15 + i];
            acc[j] += fast_tanh(a) * av;
        }
    }
#pragma unroll
    for (int j = 0; j < 5; ++j) {
        acc[j] += __shfl_xor(acc[j], 1, 64);
        acc[j] += __shfl_xor(acc[j], 2, 64);
    }
    int pred = 0;
    if (q == 0) {
        float4 s0 = ((const float4*)(sprev + (size_t)n * 8))[0];
        float s4 = sprev[(size_t)n * 8 + 4];
        float d0 = acc[0] - s0.x, d1 = acc[1] - s0.y, d2 = acc[2] - s0.z;
        float d3 = acc[3] - s0.w, d4 = acc[4] - s4;
        float ss = d0 * d0 + d1 * d1 + d2 * d2 + d3 * d3 + d4 * d4;
        float4 o0 = {acc[0], acc[1], acc[2], acc[3]};
        float4 o1 = {acc[4], 0.f, 0.f, 0.f};
        ((float4*)(snext + (size_t)n * 8))[0] = o0;
        ((float4*)(snext + (size_t)n * 8))[1] = o1;
        pred = sqrtf(ss + 1e-11f) > THRESH;
    }
    unsigned long long m = __ballot(pred);
    if ((threadIdx.x & 63) == 0 && m) atomicOr(flag_next, 1);
}

__global__ void final8_kernel(const float* __restrict__ state,  // stride 8
                              const float* __restrict__ W3, const float* __restrict__ b3,
                              const float* __restrict__ W4, const float* __restrict__ b4,
                              const int* __restrict__ kcnt,
                              float* __restrict__ out) {
    int n = blockIdx.x * blockDim.x + threadIdx.x;
    if (n == 0) out[(size_t)N_NODES * 7] = (float)(*kcnt);
    if (n >= N_NODES) return;
    float st[5];
    float4 s0 = ((const float4*)(state + (size_t)n * 8))[0];
    st[0] = s0.x; st[1] = s0.y; st[2] = s0.z; st[3] = s0.w;
    st[4] = state[(size_t)n * 8 + 4];
    float o1[10];
#pragma unroll
    for (int j = 0; j < 10; ++j) {
        float a = b3[j];
#pragma unroll
        for (int i = 0; i < 5; ++i) a += st[i] * W3[i * 10 + j];
        o1[j] = tanhf(a);
    }
    float z[7];
    float m = -1e30f;
#pragma unroll
    for (int j = 0; j < 7; ++j) {
        float a = b4[j];
#pragma unroll
        for (int i = 0; i < 10; ++i) a += o1[i] * W4[i * 7 + j];
        z[j] = a;
        m = fmaxf(m, a);
    }
    float s = 0.f;
#pragma unroll
    for (int j = 0; j < 7; ++j) { z[j] = expf(z[j] - m); s += z[j]; }
    float inv = 1.f / s;
#pragma unroll
    for (int j = 0; j < 7; ++j) out[(size_t)n * 7 + j] = z[j] * inv;
}

// ---------------- FALLBACK (R2) kernels ----------------
__global__ void init_state_kernel(const float* __restrict__ state_init,
                                  const float* __restrict__ old_init,
                                  float* __restrict__ buf0,
                                  int* __restrict__ flags) {
    int n = blockIdx.x * blockDim.x + threadIdx.x;
    if (n >= N_NODES) return;
    float ss = 0.f;
#pragma unroll
    for (int j = 0; j < 5; ++j) {
        float s = state_init[n * 5 + j];
        float o = old_init[n * 5 + j];
        buf0[n * 5 + j] = s;
        float d = s - o;
        ss += d * d;
    }
    int pred = sqrtf(ss + 1e-11f) > THRESH;
    unsigned long long m = __ballot(pred);
    if ((threadIdx.x & 63) == 0 && m) atomicOr(&flags[0], 1);
}

__global__ __launch_bounds__(256) void iter_kernel(
    const int* __restrict__ off, const int* __restrict__ perm,
    const float* __restrict__ edge_feat, const int* __restrict__ edge_src,
    const float* __restrict__ arc_vals,
    const float* __restrict__ sprev, float* __restrict__ snext,
    const float* __restrict__ W1, const float* __restrict__ b1,
    const float* __restrict__ W2, const float* __restrict__ b2,
    const int* __restrict__ flag_cur, int* __restrict__ flag_next,
    int* __restrict__ kcnt) {
    int t = blockIdx.x * blockDim.x + threadIdx.x;
    int n = t >> 1;
    if (n >= N_NODES) return;
    int half = t & 1;
    if (*flag_cur == 0) {
        if (half == 0) {
#pragma unroll
            for (int j = 0; j < 5; ++j) snext[n * 5 + j] = sprev[n * 5 + j];
        }
        return;
    }
    if (t == 0) *kcnt += 1;
    int p0 = off[n], p1 = off[n + 1];
    float acc[5] = {0.f, 0.f, 0.f, 0.f, 0.f};
    for (int p = p0 + half; p < p1; p += 2) {
        int e = perm[p];
        const float4* efp = (const float4*)(edge_feat + (size_t)e * 8);
        float4 f0 = efp[0];
        float4 f1 = efp[1];
        int src = edge_src[e];
        float av = arc_vals[e];
        float in[13];
        in[0] = f0.x; in[1] = f0.y; in[2] = f0.z; in[3] = f0.w;
        in[4] = f1.x; in[5] = f1.y; in[6] = f1.z; in[7] = f1.w;
#pragma unroll
        for (int j = 0; j < 5; ++j) in[8 + j] = sprev[src * 5 + j];
        float h1[15];
#pragma unroll
        for (int j = 0; j < 15; ++j) {
            float a = b1[j];
#pragma unroll
            for (int i = 0; i < 13; ++i) a += in[i] * W1[i * 15 + j];
            h1[j] = fast_tanh(a);
        }
#pragma unroll
        for (int j = 0; j < 5; ++j) {
            float a = b2[j];
#pragma unroll
            for (int i = 0; i < 15; ++i) a += h1[i] * W2[i * 5 + j];
            acc[j] += fast_tanh(a) * av;
        }
    }
#pragma unroll
    for (int j = 0; j < 5; ++j) acc[j] += __shfl_xor(acc[j], 1, 64);
    int pred = 0;
    if (half == 0) {
        float ss = 0.f;
#pragma unroll
        for (int j = 0; j < 5; ++j) {
            float pv = sprev[n * 5 + j];
            snext[n * 5 + j] = acc[j];
            float d = acc[j] - pv;
            ss += d * d;
        }
        pred = sqrtf(ss + 1e-11f) > THRESH;
    }
    unsigned long long m = __ballot(pred);
    if ((threadIdx.x & 63) == 0 && m) atomicOr(flag_next, 1);
}

__global__ void final_kernel(const float* __restrict__ state,
                             const float* __restrict__ W3, const float* __restrict__ b3,
                             const float* __restrict__ W4, const float* __restrict__ b4,
                             const int* __restrict__ kcnt,
                             float* __restrict__ out) {
    int n = blockIdx.x * blockDim.x + threadIdx.x;
    if (n == 0) out[(size_t)N_NODES * 7] = (float)(*kcnt);
    if (n >= N_NODES) return;
    float st[5];
#pragma unroll
    for (int j = 0; j < 5; ++j) st[j] = state[n * 5 + j];
    float o1[10];
#pragma unroll
    for (int j = 0; j < 10; ++j) {
        float a = b3[j];
#pragma unroll
        for (int i = 0; i < 5; ++i) a += st[i] * W3[i * 10 + j];
        o1[j] = tanhf(a);
    }
    float z[7];
    float m = -1e30f;
#pragma unroll
    for (int j = 0; j < 7; ++j) {
        float a = b4[j];
#pragma unroll
        for (int i = 0; i < 10; ++i) a += o1[i] * W4[i * 7 + j];
        z[j] = a;
        m = fmaxf(m, a);
    }
    float s = 0.f;
#pragma unroll
    for (int j = 0; j < 7; ++j) { z[j] = expf(z[j] - m); s += z[j]; }
    float inv = 1.f / s;
#pragma unroll
    for (int j = 0; j < 7; ++j) out[(size_t)n * 7 + j] = z[j] * inv;
}

extern "C" void kernel_launch(void* const* d_in, const int* in_sizes, int n_in,
                              void* d_out, int out_size, void* d_ws, size_t ws_size,
                              hipStream_t stream) {
    const float* edge_feat  = (const float*)d_in[0];
    const int*   edge_src   = (const int*)d_in[1];
    const int*   arc_rows   = (const int*)d_in[2];
    const float* arc_vals   = (const float*)d_in[3];
    const float* state_init = (const float*)d_in[4];
    const float* old_init   = (const float*)d_in[5];
    const float* W1 = (const float*)d_in[6];
    const float* b1 = (const float*)d_in[7];
    const float* W2 = (const float*)d_in[8];
    const float* b2 = (const float*)d_in[9];
    const float* W3 = (const float*)d_in[10];
    const float* b3 = (const float*)d_in[11];
    const float* W4 = (const float*)d_in[12];
    const float* b4 = (const float*)d_in[13];

    char* ws = (char*)d_ws;
    int nb = (N_NODES + 255) / 256;
    int eb = (N_EDGES + 255) / 256;

    if (ws_size >= WS_FULL_NEED) {
        int*   off   = (int*)(ws + 0);
        int*   cnt   = (int*)(ws + 400128);
        int*   flags = (int*)(ws + 800128);
        int*   kcnt  = flags + 51;
        float* wc    = (float*)(ws + 800384);
        float* buf0  = (float*)(ws + 801664);
        float* buf1  = (float*)(ws + 4001664);
        int2*  meta  = (int2*)(ws + 7201664);
        float* featg = (float*)(ws + 20001664);
        int*   bsum  = cnt;  // reuse cnt region start? no — need separate; use flags+64
        // small scratch for scan block sums: place after flags (52 ints), 98 ints fit in pad
        bsum = (int*)(ws + 800128 + 52 * 4);  // 800336..800728 — overlaps wconst start (800384)!
        // -> instead put bsum in the cnt pad region after N ints? cnt ends 800128 exactly.
        // Use dedicated: tail of buf1 region is free before it's written? Not safe.
        // Simplest: reuse 'off' pad (400,004..400,128 too small). Place bsum in featg
        // region (written later, after scans complete): safe by ordering.
        bsum = (int*)(ws + 20001664);

        hipLaunchKernelGGL(zero_ints, dim3(nb), dim3(256), 0, stream, cnt, N_NODES);
        hipLaunchKernelGGL(zero_ints, dim3(1), dim3(64), 0, stream, flags, 52);
        hipLaunchKernelGGL(hist_kernel, dim3(eb), dim3(256), 0, stream, arc_rows, cnt);
        hipLaunchKernelGGL(scan1_kernel, dim3(NBLK_SCAN), dim3(256), 0, stream, cnt, off, bsum);
        hipLaunchKernelGGL(scan2_kernel, dim3(1), dim3(128), 0, stream, bsum);
        hipLaunchKernelGGL(scan3_kernel, dim3(NBLK_SCAN), dim3(256), 0, stream, off, bsum);
        hipLaunchKernelGGL(zero_ints, dim3(nb), dim3(256), 0, stream, cnt, N_NODES);
        hipLaunchKernelGGL(scatter_build, dim3(eb), dim3(256), 0, stream,
                           arc_rows, edge_src, arc_vals, edge_feat, off, cnt, featg, meta);
        hipLaunchKernelGGL(wprep_kernel, dim3(1), dim3(256), 0, stream, W1, b1, W2, b2, wc);
        hipLaunchKernelGGL(init_state8_kernel, dim3(nb), dim3(256), 0, stream,
                           state_init, old_init, buf0, flags);

        int ib = (4 * N_NODES + 255) / 256;
        for (int it = 0; it < MAX_ITER; ++it) {
            const float* sp = (it & 1) ? buf1 : buf0;
            float*       sn = (it & 1) ? buf0 : buf1;
            hipLaunchKernelGGL(iter4_kernel, dim3(ib), dim3(256), 0, stream,
                               off, featg, meta, sp, sn, wc,
                               flags + it, flags + it + 1, kcnt);
        }
        hipLaunchKernelGGL(final8_kernel, dim3(nb), dim3(256), 0, stream,
                           buf0, W3, b3, W4, b4, kcnt, (float*)d_out);
    } else {
        // -------- FALLBACK: R2 structure --------
        int*   off   = (int*)(ws + 0);
        int*   cnt   = (int*)(ws + 400016);
        int*   bsum  = (int*)(ws + 800016);
        int*   flags = (int*)(ws + 800528);
        int*   kcnt  = flags + 51;
        int*   perm  = (int*)(ws + 800752);
        float* buf0  = (float*)(ws + 7200752);
        float* buf1  = (float*)(ws + 9200752);

        hipLaunchKernelGGL(zero_ints, dim3(nb), dim3(256), 0, stream, cnt, N_NODES);
        hipLaunchKernelGGL(zero_ints, dim3(1), dim3(64), 0, stream, flags, 52);
        hipLaunchKernelGGL(hist_kernel, dim3(eb), dim3(256), 0, stream, arc_rows, cnt);
        hipLaunchKernelGGL(scan1_kernel, dim3(NBLK_SCAN), dim3(256), 0, stream, cnt, off, bsum);
        hipLaunchKernelGGL(scan2_kernel, dim3(1), dim3(128), 0, stream, bsum);
        hipLaunchKernelGGL(scan3_kernel, dim3(NBLK_SCAN), dim3(256), 0, stream, off, bsum);
        hipLaunchKernelGGL(zero_ints, dim3(nb), dim3(256), 0, stream, cnt, N_NODES);
        hipLaunchKernelGGL(scatter_kernel, dim3(eb), dim3(256), 0, stream, arc_rows, off, cnt, perm);
        hipLaunchKernelGGL(init_state_kernel, dim3(nb), dim3(256), 0, stream,
                           state_init, old_init, buf0, flags);

        int ib = (2 * N_NODES + 255) / 256;
        for (int it = 0; it < MAX_ITER; ++it) {
            const float* sp = (it & 1) ? buf1 : buf0;
            float*       sn = (it & 1) ? buf0 : buf1;
            hipLaunchKernelGGL(iter_kernel, dim3(ib), dim3(256), 0, stream,
                               off, perm, edge_feat, edge_src, arc_vals,
                               sp, sn, W1, b1, W2, b2,
                               flags + it, flags + it + 1, kcnt);
        }
        hipLaunchKernelGGL(final_kernel, dim3(nb), dim3(256), 0, stream,
                           buf0, W3, b3, W4, b4, kcnt, (float*)d_out);
    }
}

// Round 4
// 4244.931 us; speedup vs baseline: 4.5003x; 1.2872x over previous
//
#include <hip/hip_runtime.h>
#include <math.h>

#define N_NODES 100000
#define N_EDGES 1600000
#define MAX_ITER 50
#define THRESH 0.01f
#define SCAN_CHUNK 1024
#define NBLK_SCAN 98   // ceil(100000/1024)

// ---------- Tier A ws layout (needs 103,201,664 B) ----------
//   off    : 0           (N+1 ints, pad to 400,128)
//   cnt    : 400,128     (N ints)
//   flags  : 800,128     (51 ints + kcnt, pad 256)
//   wc     : 800,384     (transposed W1/b1/W2/b2, 290 f, pad 1280)
//   buf0   : 801,664     (N*8 f32 padded state)
//   buf1   : 4,001,664
//   meta   : 7,201,664   (E int2, CSR order)
//   featg  : 20,001,664  (E*8 f32, CSR order)
//   eout   : 71,201,664  (5 planes * E f32 = 32 MB)  [also scan bsum scratch]
#define WS_A_NEED 103201664ULL
#define WS_B_NEED  71201664ULL   // Tier B = R3 layout (bsum scratch in featg)

__device__ __forceinline__ float fast_tanh(float x) {
    float ax = fabsf(x);
    float e = __expf(2.0f * ax);
    float r = 1.0f - 2.0f * __builtin_amdgcn_rcpf(e + 1.0f);
    return copysignf(r, x);
}

__global__ void zero_ints(int* p, int n) {
    int i = blockIdx.x * blockDim.x + threadIdx.x;
    if (i < n) p[i] = 0;
}

__global__ void hist_kernel(const int* __restrict__ rows, int* __restrict__ cnt) {
    int e = blockIdx.x * blockDim.x + threadIdx.x;
    if (e < N_EDGES) atomicAdd(&cnt[rows[e]], 1);
}

__global__ __launch_bounds__(256) void scan1_kernel(const int* __restrict__ cnt,
                                                    int* __restrict__ off,
                                                    int* __restrict__ bsum) {
    __shared__ int sm[256];
    int b = blockIdx.x, t = threadIdx.x;
    int base = b * SCAN_CHUNK + t * 4;
    int v[4];
    int tsum = 0;
#pragma unroll
    for (int j = 0; j < 4; ++j) {
        v[j] = (base + j < N_NODES) ? cnt[base + j] : 0;
        tsum += v[j];
    }
    int val = tsum;
    sm[t] = val;
    __syncthreads();
    for (int d = 1; d < 256; d <<= 1) {
        int x = (t >= d) ? sm[t - d] : 0;
        __syncthreads();
        val += x;
        sm[t] = val;
        __syncthreads();
    }
    int run = val - tsum;
#pragma unroll
    for (int j = 0; j < 4; ++j) {
        if (base + j < N_NODES) off[base + j] = run;
        run += v[j];
    }
    if (t == 255) bsum[b] = val;
}

__global__ __launch_bounds__(128) void scan2_kernel(int* __restrict__ bsum) {
    __shared__ int sm[128];
    int t = threadIdx.x;
    int v = (t < NBLK_SCAN) ? bsum[t] : 0;
    int val = v;
    sm[t] = val;
    __syncthreads();
    for (int d = 1; d < 128; d <<= 1) {
        int x = (t >= d) ? sm[t - d] : 0;
        __syncthreads();
        val += x;
        sm[t] = val;
        __syncthreads();
    }
    if (t < NBLK_SCAN) bsum[t] = val - v;
}

__global__ __launch_bounds__(256) void scan3_kernel(int* __restrict__ off,
                                                    const int* __restrict__ bsum) {
    int b = blockIdx.x, t = threadIdx.x;
    int add = bsum[b];
    int base = b * SCAN_CHUNK + t * 4;
#pragma unroll
    for (int j = 0; j < 4; ++j)
        if (base + j < N_NODES) off[base + j] += add;
    if (b == 0 && t == 0) off[N_NODES] = N_EDGES;
}

__global__ void scatter_build(const int* __restrict__ rows,
                              const int* __restrict__ esrc,
                              const float* __restrict__ evals,
                              const float* __restrict__ efeat,
                              const int* __restrict__ off,
                              int* __restrict__ cur,
                              float* __restrict__ featg,
                              int2* __restrict__ meta) {
    int e = blockIdx.x * blockDim.x + threadIdx.x;
    if (e >= N_EDGES) return;
    int r = rows[e];
    int p = off[r] + atomicAdd(&cur[r], 1);
    const float4* fp = (const float4*)(efeat + (size_t)e * 8);
    float4 a = fp[0], b = fp[1];
    float4* gp = (float4*)(featg + (size_t)p * 8);
    gp[0] = a; gp[1] = b;
    meta[p] = make_int2(esrc[e], __float_as_int(evals[e]));
}

__global__ void scatter_kernel(const int* __restrict__ rows,
                               const int* __restrict__ off,
                               int* __restrict__ cur,
                               int* __restrict__ perm) {
    int e = blockIdx.x * blockDim.x + threadIdx.x;
    if (e >= N_EDGES) return;
    int r = rows[e];
    int p = off[r] + atomicAdd(&cur[r], 1);
    perm[p] = e;
}

__global__ void wprep_kernel(const float* __restrict__ W1, const float* __restrict__ b1,
                             const float* __restrict__ W2, const float* __restrict__ b2,
                             float* __restrict__ wc) {
    int t = threadIdx.x;
    for (int idx = t; idx < 195; idx += 256) { int j = idx / 13, i = idx % 13; wc[idx] = W1[i * 15 + j]; }
    for (int idx = t; idx < 15; idx += 256) wc[195 + idx] = b1[idx];
    for (int idx = t; idx < 75; idx += 256) { int j = idx / 15, i = idx % 15; wc[210 + idx] = W2[i * 5 + j]; }
    for (int idx = t; idx < 5; idx += 256) wc[285 + idx] = b2[idx];
}

__global__ void init_state8_kernel(const float* __restrict__ state_init,
                                   const float* __restrict__ old_init,
                                   float* __restrict__ buf0,
                                   int* __restrict__ flags) {
    int n = blockIdx.x * blockDim.x + threadIdx.x;
    if (n >= N_NODES) return;
    float ss = 0.f;
    float s[5];
#pragma unroll
    for (int j = 0; j < 5; ++j) {
        s[j] = state_init[n * 5 + j];
        float d = s[j] - old_init[n * 5 + j];
        ss += d * d;
    }
    float4 o0 = {s[0], s[1], s[2], s[3]};
    float4 o1 = {s[4], 0.f, 0.f, 0.f};
    ((float4*)(buf0 + (size_t)n * 8))[0] = o0;
    ((float4*)(buf0 + (size_t)n * 8))[1] = o1;
    int pred = sqrtf(ss + 1e-11f) > THRESH;
    unsigned long long m = __ballot(pred);
    if ((threadIdx.x & 63) == 0 && m) atomicOr(&flags[0], 1);
}

// ---------------- Tier A hot kernels ----------------
// One thread per CSR slot: sequential featg/meta, one independent state gather,
// full-unroll MLP, coalesced SoA output. Perfectly load-balanced.
__global__ __launch_bounds__(256) void edge_mlp_kernel(
    const float* __restrict__ featg,
    const int2* __restrict__ meta,
    const float* __restrict__ sprev,   // stride 8
    float* __restrict__ eout,          // 5 planes of N_EDGES
    const float* __restrict__ wc,
    const int* __restrict__ flag_cur) {
    if (*flag_cur == 0) return;
    int p = blockIdx.x * blockDim.x + threadIdx.x;
    if (p >= N_EDGES) return;
    const float* W1T = wc;          // [15][13]
    const float* B1  = wc + 195;
    const float* W2T = wc + 210;    // [5][15]
    const float* B2  = wc + 285;

    const float4* fp = (const float4*)(featg + (size_t)p * 8);
    float4 f0 = fp[0], f1 = fp[1];
    int2 mv = meta[p];
    int src = mv.x;
    float av = __int_as_float(mv.y);
    float4 s0 = ((const float4*)(sprev + (size_t)src * 8))[0];
    float s4 = sprev[(size_t)src * 8 + 4];
    float in[13] = {f0.x, f0.y, f0.z, f0.w, f1.x, f1.y, f1.z, f1.w,
                    s0.x, s0.y, s0.z, s0.w, s4};
    float h1[15];
#pragma unroll
    for (int j = 0; j < 15; ++j) {
        float a = B1[j];
#pragma unroll
        for (int i = 0; i < 13; ++i) a += in[i] * W1T[j * 13 + i];
        h1[j] = fast_tanh(a);
    }
#pragma unroll
    for (int j = 0; j < 5; ++j) {
        float a = B2[j];
#pragma unroll
        for (int i = 0; i < 15; ++i) a += h1[i] * W2T[j * 15 + i];
        eout[(size_t)j * N_EDGES + p] = fast_tanh(a) * av;
    }
}

// 2 threads per node, contiguous-run reduction over 5 SoA planes.
__global__ __launch_bounds__(256) void node_reduce_kernel(
    const int* __restrict__ off,
    const float* __restrict__ eout,
    const float* __restrict__ sprev,   // stride 8
    float* __restrict__ snext,         // stride 8
    const int* __restrict__ flag_cur, int* __restrict__ flag_next,
    int* __restrict__ kcnt) {
    int t = blockIdx.x * blockDim.x + threadIdx.x;
    int n = t >> 1;
    if (n >= N_NODES) return;
    int half = t & 1;
    if (*flag_cur == 0) {
        if (half == 0) {
            float4 a = ((const float4*)(sprev + (size_t)n * 8))[0];
            float4 b = ((const float4*)(sprev + (size_t)n * 8))[1];
            ((float4*)(snext + (size_t)n * 8))[0] = a;
            ((float4*)(snext + (size_t)n * 8))[1] = b;
        }
        return;
    }
    if (t == 0) *kcnt += 1;
    int p0 = off[n], p1 = off[n + 1];
    float acc[5] = {0.f, 0.f, 0.f, 0.f, 0.f};
    for (int p = p0 + half; p < p1; p += 2) {
#pragma unroll
        for (int j = 0; j < 5; ++j) acc[j] += eout[(size_t)j * N_EDGES + p];
    }
#pragma unroll
    for (int j = 0; j < 5; ++j) acc[j] += __shfl_xor(acc[j], 1, 64);
    int pred = 0;
    if (half == 0) {
        float4 s0 = ((const float4*)(sprev + (size_t)n * 8))[0];
        float s4 = sprev[(size_t)n * 8 + 4];
        float d0 = acc[0] - s0.x, d1 = acc[1] - s0.y, d2 = acc[2] - s0.z;
        float d3 = acc[3] - s0.w, d4 = acc[4] - s4;
        float ss = d0 * d0 + d1 * d1 + d2 * d2 + d3 * d3 + d4 * d4;
        float4 o0 = {acc[0], acc[1], acc[2], acc[3]};
        float4 o1 = {acc[4], 0.f, 0.f, 0.f};
        ((float4*)(snext + (size_t)n * 8))[0] = o0;
        ((float4*)(snext + (size_t)n * 8))[1] = o1;
        pred = sqrtf(ss + 1e-11f) > THRESH;
    }
    unsigned long long m = __ballot(pred);
    if ((threadIdx.x & 63) == 0 && m) atomicOr(flag_next, 1);
}

// ---------------- Tier B hot kernel (R3) ----------------
__global__ __launch_bounds__(256) void iter4_kernel(
    const int* __restrict__ off,
    const float* __restrict__ featg,
    const int2* __restrict__ meta,
    const float* __restrict__ sprev,
    float* __restrict__ snext,
    const float* __restrict__ wc,
    const int* __restrict__ flag_cur, int* __restrict__ flag_next,
    int* __restrict__ kcnt) {
    int t = blockIdx.x * blockDim.x + threadIdx.x;
    int n = t >> 2;
    if (n >= N_NODES) return;
    int q = t & 3;
    if (*flag_cur == 0) {
        if (q == 0) {
            float4 a = ((const float4*)(sprev + (size_t)n * 8))[0];
            float4 b = ((const float4*)(sprev + (size_t)n * 8))[1];
            ((float4*)(snext + (size_t)n * 8))[0] = a;
            ((float4*)(snext + (size_t)n * 8))[1] = b;
        }
        return;
    }
    if (t == 0) *kcnt += 1;
    const float* W1T = wc;
    const float* B1  = wc + 195;
    const float* W2T = wc + 210;
    const float* B2  = wc + 285;
    int p0 = off[n], p1 = off[n + 1];
    float acc[5] = {0.f, 0.f, 0.f, 0.f, 0.f};
    for (int p = p0 + q; p < p1; p += 4) {
        const float4* fp = (const float4*)(featg + (size_t)p * 8);
        float4 f0 = fp[0], f1 = fp[1];
        int2 mv = meta[p];
        int src = mv.x;
        float av = __int_as_float(mv.y);
        float4 s0 = ((const float4*)(sprev + (size_t)src * 8))[0];
        float s4 = sprev[(size_t)src * 8 + 4];
        float in[13] = {f0.x, f0.y, f0.z, f0.w, f1.x, f1.y, f1.z, f1.w,
                        s0.x, s0.y, s0.z, s0.w, s4};
        float h1[15];
#pragma unroll
        for (int j = 0; j < 15; ++j) {
            float a = B1[j];
#pragma unroll
            for (int i = 0; i < 13; ++i) a += in[i] * W1T[j * 13 + i];
            h1[j] = fast_tanh(a);
        }
#pragma unroll
        for (int j = 0; j < 5; ++j) {
            float a = B2[j];
#pragma unroll
            for (int i = 0; i < 15; ++i) a += h1[i] * W2T[j * 15 + i];
            acc[j] += fast_tanh(a) * av;
        }
    }
#pragma unroll
    for (int j = 0; j < 5; ++j) {
        acc[j] += __shfl_xor(acc[j], 1, 64);
        acc[j] += __shfl_xor(acc[j], 2, 64);
    }
    int pred = 0;
    if (q == 0) {
        float4 s0 = ((const float4*)(sprev + (size_t)n * 8))[0];
        float s4 = sprev[(size_t)n * 8 + 4];
        float d0 = acc[0] - s0.x, d1 = acc[1] - s0.y, d2 = acc[2] - s0.z;
        float d3 = acc[3] - s0.w, d4 = acc[4] - s4;
        float ss = d0 * d0 + d1 * d1 + d2 * d2 + d3 * d3 + d4 * d4;
        float4 o0 = {acc[0], acc[1], acc[2], acc[3]};
        float4 o1 = {acc[4], 0.f, 0.f, 0.f};
        ((float4*)(snext + (size_t)n * 8))[0] = o0;
        ((float4*)(snext + (size_t)n * 8))[1] = o1;
        pred = sqrtf(ss + 1e-11f) > THRESH;
    }
    unsigned long long m = __ballot(pred);
    if ((threadIdx.x & 63) == 0 && m) atomicOr(flag_next, 1);
}

__global__ void final8_kernel(const float* __restrict__ state,
                              const float* __restrict__ W3, const float* __restrict__ b3,
                              const float* __restrict__ W4, const float* __restrict__ b4,
                              const int* __restrict__ kcnt,
                              float* __restrict__ out) {
    int n = blockIdx.x * blockDim.x + threadIdx.x;
    if (n == 0) out[(size_t)N_NODES * 7] = (float)(*kcnt);
    if (n >= N_NODES) return;
    float st[5];
    float4 s0 = ((const float4*)(state + (size_t)n * 8))[0];
    st[0] = s0.x; st[1] = s0.y; st[2] = s0.z; st[3] = s0.w;
    st[4] = state[(size_t)n * 8 + 4];
    float o1[10];
#pragma unroll
    for (int j = 0; j < 10; ++j) {
        float a = b3[j];
#pragma unroll
        for (int i = 0; i < 5; ++i) a += st[i] * W3[i * 10 + j];
        o1[j] = tanhf(a);
    }
    float z[7];
    float m = -1e30f;
#pragma unroll
    for (int j = 0; j < 7; ++j) {
        float a = b4[j];
#pragma unroll
        for (int i = 0; i < 10; ++i) a += o1[i] * W4[i * 7 + j];
        z[j] = a;
        m = fmaxf(m, a);
    }
    float s = 0.f;
#pragma unroll
    for (int j = 0; j < 7; ++j) { z[j] = expf(z[j] - m); s += z[j]; }
    float inv = 1.f / s;
#pragma unroll
    for (int j = 0; j < 7; ++j) out[(size_t)n * 7 + j] = z[j] * inv;
}

// ---------------- Tier C (R2) kernels ----------------
__global__ void init_state_kernel(const float* __restrict__ state_init,
                                  const float* __restrict__ old_init,
                                  float* __restrict__ buf0,
                                  int* __restrict__ flags) {
    int n = blockIdx.x * blockDim.x + threadIdx.x;
    if (n >= N_NODES) return;
    float ss = 0.f;
#pragma unroll
    for (int j = 0; j < 5; ++j) {
        float s = state_init[n * 5 + j];
        float o = old_init[n * 5 + j];
        buf0[n * 5 + j] = s;
        float d = s - o;
        ss += d * d;
    }
    int pred = sqrtf(ss + 1e-11f) > THRESH;
    unsigned long long m = __ballot(pred);
    if ((threadIdx.x & 63) == 0 && m) atomicOr(&flags[0], 1);
}

__global__ __launch_bounds__(256) void iter_kernel(
    const int* __restrict__ off, const int* __restrict__ perm,
    const float* __restrict__ edge_feat, const int* __restrict__ edge_src,
    const float* __restrict__ arc_vals,
    const float* __restrict__ sprev, float* __restrict__ snext,
    const float* __restrict__ W1, const float* __restrict__ b1,
    const float* __restrict__ W2, const float* __restrict__ b2,
    const int* __restrict__ flag_cur, int* __restrict__ flag_next,
    int* __restrict__ kcnt) {
    int t = blockIdx.x * blockDim.x + threadIdx.x;
    int n = t >> 1;
    if (n >= N_NODES) return;
    int half = t & 1;
    if (*flag_cur == 0) {
        if (half == 0) {
#pragma unroll
            for (int j = 0; j < 5; ++j) snext[n * 5 + j] = sprev[n * 5 + j];
        }
        return;
    }
    if (t == 0) *kcnt += 1;
    int p0 = off[n], p1 = off[n + 1];
    float acc[5] = {0.f, 0.f, 0.f, 0.f, 0.f};
    for (int p = p0 + half; p < p1; p += 2) {
        int e = perm[p];
        const float4* efp = (const float4*)(edge_feat + (size_t)e * 8);
        float4 f0 = efp[0];
        float4 f1 = efp[1];
        int src = edge_src[e];
        float av = arc_vals[e];
        float in[13];
        in[0] = f0.x; in[1] = f0.y; in[2] = f0.z; in[3] = f0.w;
        in[4] = f1.x; in[5] = f1.y; in[6] = f1.z; in[7] = f1.w;
#pragma unroll
        for (int j = 0; j < 5; ++j) in[8 + j] = sprev[src * 5 + j];
        float h1[15];
#pragma unroll
        for (int j = 0; j < 15; ++j) {
            float a = b1[j];
#pragma unroll
            for (int i = 0; i < 13; ++i) a += in[i] * W1[i * 15 + j];
            h1[j] = fast_tanh(a);
        }
#pragma unroll
        for (int j = 0; j < 5; ++j) {
            float a = b2[j];
#pragma unroll
            for (int i = 0; i < 15; ++i) a += h1[i] * W2[i * 5 + j];
            acc[j] += fast_tanh(a) * av;
        }
    }
#pragma unroll
    for (int j = 0; j < 5; ++j) acc[j] += __shfl_xor(acc[j], 1, 64);
    int pred = 0;
    if (half == 0) {
        float ss = 0.f;
#pragma unroll
        for (int j = 0; j < 5; ++j) {
            float pv = sprev[n * 5 + j];
            snext[n * 5 + j] = acc[j];
            float d = acc[j] - pv;
            ss += d * d;
        }
        pred = sqrtf(ss + 1e-11f) > THRESH;
    }
    unsigned long long m = __ballot(pred);
    if ((threadIdx.x & 63) == 0 && m) atomicOr(flag_next, 1);
}

__global__ void final_kernel(const float* __restrict__ state,
                             const float* __restrict__ W3, const float* __restrict__ b3,
                             const float* __restrict__ W4, const float* __restrict__ b4,
                             const int* __restrict__ kcnt,
                             float* __restrict__ out) {
    int n = blockIdx.x * blockDim.x + threadIdx.x;
    if (n == 0) out[(size_t)N_NODES * 7] = (float)(*kcnt);
    if (n >= N_NODES) return;
    float st[5];
#pragma unroll
    for (int j = 0; j < 5; ++j) st[j] = state[n * 5 + j];
    float o1[10];
#pragma unroll
    for (int j = 0; j < 10; ++j) {
        float a = b3[j];
#pragma unroll
        for (int i = 0; i < 5; ++i) a += st[i] * W3[i * 10 + j];
        o1[j] = tanhf(a);
    }
    float z[7];
    float m = -1e30f;
#pragma unroll
    for (int j = 0; j < 7; ++j) {
        float a = b4[j];
#pragma unroll
        for (int i = 0; i < 10; ++i) a += o1[i] * W4[i * 7 + j];
        z[j] = a;
        m = fmaxf(m, a);
    }
    float s = 0.f;
#pragma unroll
    for (int j = 0; j < 7; ++j) { z[j] = expf(z[j] - m); s += z[j]; }
    float inv = 1.f / s;
#pragma unroll
    for (int j = 0; j < 7; ++j) out[(size_t)n * 7 + j] = z[j] * inv;
}

extern "C" void kernel_launch(void* const* d_in, const int* in_sizes, int n_in,
                              void* d_out, int out_size, void* d_ws, size_t ws_size,
                              hipStream_t stream) {
    const float* edge_feat  = (const float*)d_in[0];
    const int*   edge_src   = (const int*)d_in[1];
    const int*   arc_rows   = (const int*)d_in[2];
    const float* arc_vals   = (const float*)d_in[3];
    const float* state_init = (const float*)d_in[4];
    const float* old_init   = (const float*)d_in[5];
    const float* W1 = (const float*)d_in[6];
    const float* b1 = (const float*)d_in[7];
    const float* W2 = (const float*)d_in[8];
    const float* b2 = (const float*)d_in[9];
    const float* W3 = (const float*)d_in[10];
    const float* b3 = (const float*)d_in[11];
    const float* W4 = (const float*)d_in[12];
    const float* b4 = (const float*)d_in[13];

    char* ws = (char*)d_ws;
    int nb = (N_NODES + 255) / 256;
    int eb = (N_EDGES + 255) / 256;

    if (ws_size >= WS_A_NEED) {
        int*   off   = (int*)(ws + 0);
        int*   cnt   = (int*)(ws + 400128);
        int*   flags = (int*)(ws + 800128);
        int*   kcnt  = flags + 51;
        float* wc    = (float*)(ws + 800384);
        float* buf0  = (float*)(ws + 801664);
        float* buf1  = (float*)(ws + 4001664);
        int2*  meta  = (int2*)(ws + 7201664);
        float* featg = (float*)(ws + 20001664);
        float* eout  = (float*)(ws + 71201664);
        int*   bsum  = (int*)(ws + 71201664);  // scratch; dead before eout is written

        hipLaunchKernelGGL(zero_ints, dim3(nb), dim3(256), 0, stream, cnt, N_NODES);
        hipLaunchKernelGGL(zero_ints, dim3(1), dim3(64), 0, stream, flags, 52);
        hipLaunchKernelGGL(hist_kernel, dim3(eb), dim3(256), 0, stream, arc_rows, cnt);
        hipLaunchKernelGGL(scan1_kernel, dim3(NBLK_SCAN), dim3(256), 0, stream, cnt, off, bsum);
        hipLaunchKernelGGL(scan2_kernel, dim3(1), dim3(128), 0, stream, bsum);
        hipLaunchKernelGGL(scan3_kernel, dim3(NBLK_SCAN), dim3(256), 0, stream, off, bsum);
        hipLaunchKernelGGL(zero_ints, dim3(nb), dim3(256), 0, stream, cnt, N_NODES);
        hipLaunchKernelGGL(scatter_build, dim3(eb), dim3(256), 0, stream,
                           arc_rows, edge_src, arc_vals, edge_feat, off, cnt, featg, meta);
        hipLaunchKernelGGL(wprep_kernel, dim3(1), dim3(256), 0, stream, W1, b1, W2, b2, wc);
        hipLaunchKernelGGL(init_state8_kernel, dim3(nb), dim3(256), 0, stream,
                           state_init, old_init, buf0, flags);

        int rb = (2 * N_NODES + 255) / 256;
        for (int it = 0; it < MAX_ITER; ++it) {
            const float* sp = (it & 1) ? buf1 : buf0;
            float*       sn = (it & 1) ? buf0 : buf1;
            hipLaunchKernelGGL(edge_mlp_kernel, dim3(eb), dim3(256), 0, stream,
                               featg, meta, sp, eout, wc, flags + it);
            hipLaunchKernelGGL(node_reduce_kernel, dim3(rb), dim3(256), 0, stream,
                               off, eout, sp, sn, flags + it, flags + it + 1, kcnt);
        }
        hipLaunchKernelGGL(final8_kernel, dim3(nb), dim3(256), 0, stream,
                           buf0, W3, b3, W4, b4, kcnt, (float*)d_out);
    } else if (ws_size >= WS_B_NEED) {
        int*   off   = (int*)(ws + 0);
        int*   cnt   = (int*)(ws + 400128);
        int*   flags = (int*)(ws + 800128);
        int*   kcnt  = flags + 51;
        float* wc    = (float*)(ws + 800384);
        float* buf0  = (float*)(ws + 801664);
        float* buf1  = (float*)(ws + 4001664);
        int2*  meta  = (int2*)(ws + 7201664);
        float* featg = (float*)(ws + 20001664);
        int*   bsum  = (int*)(ws + 20001664);  // scratch; dead before featg written

        hipLaunchKernelGGL(zero_ints, dim3(nb), dim3(256), 0, stream, cnt, N_NODES);
        hipLaunchKernelGGL(zero_ints, dim3(1), dim3(64), 0, stream, flags, 52);
        hipLaunchKernelGGL(hist_kernel, dim3(eb), dim3(256), 0, stream, arc_rows, cnt);
        hipLaunchKernelGGL(scan1_kernel, dim3(NBLK_SCAN), dim3(256), 0, stream, cnt, off, bsum);
        hipLaunchKernelGGL(scan2_kernel, dim3(1), dim3(128), 0, stream, bsum);
        hipLaunchKernelGGL(scan3_kernel, dim3(NBLK_SCAN), dim3(256), 0, stream, off, bsum);
        hipLaunchKernelGGL(zero_ints, dim3(nb), dim3(256), 0, stream, cnt, N_NODES);
        hipLaunchKernelGGL(scatter_build, dim3(eb), dim3(256), 0, stream,
                           arc_rows, edge_src, arc_vals, edge_feat, off, cnt, featg, meta);
        hipLaunchKernelGGL(wprep_kernel, dim3(1), dim3(256), 0, stream, W1, b1, W2, b2, wc);
        hipLaunchKernelGGL(init_state8_kernel, dim3(nb), dim3(256), 0, stream,
                           state_init, old_init, buf0, flags);

        int ib = (4 * N_NODES + 255) / 256;
        for (int it = 0; it < MAX_ITER; ++it) {
            const float* sp = (it & 1) ? buf1 : buf0;
            float*       sn = (it & 1) ? buf0 : buf1;
            hipLaunchKernelGGL(iter4_kernel, dim3(ib), dim3(256), 0, stream,
                               off, featg, meta, sp, sn, wc,
                               flags + it, flags + it + 1, kcnt);
        }
        hipLaunchKernelGGL(final8_kernel, dim3(nb), dim3(256), 0, stream,
                           buf0, W3, b3, W4, b4, kcnt, (float*)d_out);
    } else {
        int*   off   = (int*)(ws + 0);
        int*   cnt   = (int*)(ws + 400016);
        int*   bsum  = (int*)(ws + 800016);
        int*   flags = (int*)(ws + 800528);
        int*   kcnt  = flags + 51;
        int*   perm  = (int*)(ws + 800752);
        float* buf0  = (float*)(ws + 7200752);
        float* buf1  = (float*)(ws + 9200752);

        hipLaunchKernelGGL(zero_ints, dim3(nb), dim3(256), 0, stream, cnt, N_NODES);
        hipLaunchKernelGGL(zero_ints, dim3(1), dim3(64), 0, stream, flags, 52);
        hipLaunchKernelGGL(hist_kernel, dim3(eb), dim3(256), 0, stream, arc_rows, cnt);
        hipLaunchKernelGGL(scan1_kernel, dim3(NBLK_SCAN), dim3(256), 0, stream, cnt, off, bsum);
        hipLaunchKernelGGL(scan2_kernel, dim3(1), dim3(128), 0, stream, bsum);
        hipLaunchKernelGGL(scan3_kernel, dim3(NBLK_SCAN), dim3(256), 0, stream, off, bsum);
        hipLaunchKernelGGL(zero_ints, dim3(nb), dim3(256), 0, stream, cnt, N_NODES);
        hipLaunchKernelGGL(scatter_kernel, dim3(eb), dim3(256), 0, stream, arc_rows, off, cnt, perm);
        hipLaunchKernelGGL(init_state_kernel, dim3(nb), dim3(256), 0, stream,
                           state_init, old_init, buf0, flags);

        int ib = (2 * N_NODES + 255) / 256;
        for (int it = 0; it < MAX_ITER; ++it) {
            const float* sp = (it & 1) ? buf1 : buf0;
            float*       sn = (it & 1) ? buf0 : buf1;
            hipLaunchKernelGGL(iter_kernel, dim3(ib), dim3(256), 0, stream,
                               off, perm, edge_feat, edge_src, arc_vals,
                               sp, sn, W1, b1, W2, b2,
                               flags + it, flags + it + 1, kcnt);
        }
        hipLaunchKernelGGL(final_kernel, dim3(nb), dim3(256), 0, stream,
                           buf0, W3, b3, W4, b4, kcnt, (float*)d_out);
    }
}